// Round 18
// baseline (188.671 us; speedup 1.0000x reference)
//
#include <hip/hip_runtime.h>
#include <hip/hip_fp16.h>

#define B_  32
#define N_  256
#define HS_ 768
#define NH_ 32
#define D_  24
#define M_  (B_*N_)   // 8192
#define NQKU 1664     // q 768 | k 768 | u 96 | pad 32

typedef unsigned short us8 __attribute__((ext_vector_type(8)));
typedef unsigned short us4v __attribute__((ext_vector_type(4)));
typedef _Float16 f16x8 __attribute__((ext_vector_type(8)));
typedef float f32x4 __attribute__((ext_vector_type(4)));

__device__ __forceinline__ unsigned short f2h(float x){
  return __half_as_ushort(__float2half(x));
}
__device__ __forceinline__ float h2f(unsigned short u){
  return __half2float(__ushort_as_half(u));
}
__device__ __forceinline__ void gload16(const void* g, void* l){
  __builtin_amdgcn_global_load_lds(
      (const __attribute__((address_space(1))) void*)g,
      (__attribute__((address_space(3))) void*)l, 16, 0, 0);
}
__device__ __forceinline__ void pin4(float4 &v){
  asm volatile("" : "+v"(v.x), "+v"(v.y), "+v"(v.z), "+v"(v.w));
}
__device__ __forceinline__ float fexp2(float x){
  float r; asm("v_exp_f32 %0, %1" : "=v"(r) : "v"(x)); return r;
}
// cross-half (lane ^ 32) add via v_permlane32_swap (VALU pipe, not DS)
__device__ __forceinline__ float red32(float v, int hi){
  float a = v, b = v;
  asm("v_permlane32_swap_b32 %0, %1" : "+v"(a), "+v"(b));
  return v + (hi ? a : b);
}

// ---------------- fp32 -> fp16-bits conversion ----------------
__global__ __launch_bounds__(256) void cvt_kernel(const float* __restrict__ in,
                                                  unsigned short* __restrict__ out, int n4){
  int i = blockIdx.x*256 + threadIdx.x;
  if (i >= n4) return;
  float4 v = ((const float4*)in)[i];
  ushort4 o;
  o.x = f2h(v.x); o.y = f2h(v.y); o.z = f2h(v.z); o.w = f2h(v.w);
  ((ushort4*)out)[i] = o;
}

// ---------------- Wu_c[h,k] = sum_d Wf_c[h*24+d]*Wv[h*24+d,k]; bu_c[h]; zws ----------------
__global__ __launch_bounds__(256) void wuprep_kernel(
    const float* __restrict__ Wv, const float* __restrict__ bvv,
    const float* __restrict__ Wf1, const float* __restrict__ Wf2, const float* __restrict__ Wf3,
    unsigned short* __restrict__ wu,   // 128 rows x 768 (rows >=96 zero pad)
    float* __restrict__ bu,            // [128]
    unsigned short* __restrict__ zws)  // 256B zeros
{
  int r = blockIdx.x;           // 0..127
  unsigned short* dst = wu + (size_t)r*768;
  int k = threadIdx.x;
  if (r == 0 && k < 16) ((us8*)zws)[k] = (us8){0,0,0,0,0,0,0,0};
  if (r < 96){
    int c = r >> 5, h = r & 31;
    const float* wf = (c == 0 ? Wf1 : c == 1 ? Wf2 : Wf3) + h*D_;
    float wfl[24];
#pragma unroll
    for (int d = 0; d < 24; d++) wfl[d] = wf[d];
    for (int kk = k; kk < 768; kk += 256){
      float s = 0.f;
#pragma unroll
      for (int d = 0; d < 24; d++) s += wfl[d]*Wv[(size_t)(h*24 + d)*768 + kk];
      dst[kk] = f2h(s);
    }
    if (k == 0){
      float s = 0.f;
      for (int d = 0; d < 24; d++) s += bvv[h*24 + d]*wfl[d];
      bu[r] = s;
    }
  } else {
    for (int kk = k; kk < 768; kk += 256) dst[kk] = 0;
    if (k == 0) bu[r] = 0.f;
  }
}

// ---------------- GEMM 128x128, BK=64, global_load_lds, XOR-swizzled LDS ----------------
// mode 0: C row-major (+gelu). mode 1 (N=1664): tiles 0-5 -> q head-major,
// 6-11 -> k head-major, 12 -> u16 [bh][n][4] fp16 (cols 1632+ dropped).
__global__ __launch_bounds__(256) void gemm128_kernel(
    const unsigned short* __restrict__ A, const unsigned short* __restrict__ W,
    const float* __restrict__ b0, const float* __restrict__ b1, const float* __restrict__ b2,
    unsigned short* __restrict__ C, unsigned short* __restrict__ qkvh,
    unsigned short* __restrict__ u16,
    int M, int N, int K, int dogelu, int mode)
{
  __shared__ unsigned short As[128*64];
  __shared__ unsigned short Bs[128*64];
  int gswz = blockIdx.x;
  int chunkg = gridDim.x >> 3;
  int bid = (gswz & 7)*chunkg + (gswz >> 3);
  int tid = threadIdx.x;
  int nT = N >> 7;
  int tm = bid / nT;
  int tn = bid - tm*nT;
  int wave = tid >> 6, lane = tid & 63;
  int wm = (wave >> 1) << 6;
  int wn = (wave & 1) << 6;
  int fr = lane & 15;
  int g  = lane >> 4;

  size_t aoff[4], woff[4];
  int ldsb[4];
#pragma unroll
  for (int s4 = 0; s4 < 4; s4++){
    int ob = s4*4096 + tid*16;
    int r  = ob >> 7;
    int p  = (ob >> 4) & 7;
    int l  = p ^ (r & 7);
    aoff[s4] = ((size_t)(tm*128 + r)*K)*2 + l*16;
    woff[s4] = ((size_t)(tn*128 + r)*K)*2 + l*16;
    ldsb[s4] = s4*4096 + wave*1024;
  }
  const char* Ab = (const char*)A;
  const char* Wb = (const char*)W;
  char* AsB = (char*)As;
  char* BsB = (char*)Bs;

  f32x4 acc[4][4];
#pragma unroll
  for (int m = 0; m < 4; m++)
#pragma unroll
    for (int n = 0; n < 4; n++) acc[m][n] = (f32x4){0.f,0.f,0.f,0.f};

  for (int k0 = 0; k0 < K; k0 += 64){
    size_t kb = (size_t)k0*2;
#pragma unroll
    for (int s4 = 0; s4 < 4; s4++) gload16(Ab + aoff[s4] + kb, AsB + ldsb[s4]);
#pragma unroll
    for (int s4 = 0; s4 < 4; s4++) gload16(Wb + woff[s4] + kb, BsB + ldsb[s4]);
    __syncthreads();

    f16x8 af[4], bf[4];
#pragma unroll
    for (int m = 0; m < 4; m++){
      int row = wm + m*16 + fr;
      af[m] = __builtin_bit_cast(f16x8, *(const us8*)(AsB + row*128 + ((g ^ (row & 7))*16)));
    }
#pragma unroll
    for (int n = 0; n < 4; n++){
      int row = wn + n*16 + fr;
      bf[n] = __builtin_bit_cast(f16x8, *(const us8*)(BsB + row*128 + ((g ^ (row & 7))*16)));
    }
#pragma unroll
    for (int m = 0; m < 4; m++)
#pragma unroll
      for (int n = 0; n < 4; n++)
        acc[m][n] = __builtin_amdgcn_mfma_f32_16x16x32_f16(af[m], bf[n], acc[m][n], 0, 0, 0);

#pragma unroll
    for (int m = 0; m < 4; m++){
      int row = wm + m*16 + fr;
      af[m] = __builtin_bit_cast(f16x8, *(const us8*)(AsB + row*128 + (((g+4) ^ (row & 7))*16)));
    }
#pragma unroll
    for (int n = 0; n < 4; n++){
      int row = wn + n*16 + fr;
      bf[n] = __builtin_bit_cast(f16x8, *(const us8*)(BsB + row*128 + (((g+4) ^ (row & 7))*16)));
    }
#pragma unroll
    for (int m = 0; m < 4; m++)
#pragma unroll
      for (int n = 0; n < 4; n++)
        acc[m][n] = __builtin_amdgcn_mfma_f32_16x16x32_f16(af[m], bf[n], acc[m][n], 0, 0, 0);
    __syncthreads();
  }

  if (mode == 0){
    const float* bp = b0;
#pragma unroll
    for (int n = 0; n < 4; n++){
      int col = tn*128 + wn + n*16 + fr;
      float bv = bp[col];
#pragma unroll
      for (int m = 0; m < 4; m++){
        int row = tm*128 + wm + m*16 + g*4;
#pragma unroll
        for (int q = 0; q < 4; q++){
          float v = acc[m][n][q] + bv;
          if (dogelu) v = 0.5f*v*(1.0f + erff(v*0.70710678118654752f));
          C[(size_t)(row + q)*N + col] = f2h(v);
        }
      }
    }
  } else {
    int which = (tn < 6) ? 0 : (tn < 12) ? 1 : 2;
    if (which < 2){
      const float* bp = which ? (b1 - 768) : b0;
#pragma unroll
      for (int n = 0; n < 4; n++){
        int col = tn*128 + wn + n*16 + fr;
        float bv = bp[col];
        int hd = col - which*768;
        int hh = hd / 24;
        int dd = hd - hh*24;
#pragma unroll
        for (int m = 0; m < 4; m++){
          int row = tm*128 + wm + m*16 + g*4;
          size_t hmbase = ((size_t)(which*1024 + (row >> 8)*32 + hh))*6144 + (row & 255)*24 + dd;
#pragma unroll
          for (int q = 0; q < 4; q++)
            qkvh[hmbase + q*24] = f2h(acc[m][n][q] + bv);
        }
      }
    } else {
#pragma unroll
      for (int n = 0; n < 4; n++){
        int col = tn*128 + wn + n*16 + fr;
        int cu = col - 1536;
        if (cu < 96){
          int c = cu >> 5, hh = cu & 31;
          float bv = b2[cu];
#pragma unroll
          for (int m = 0; m < 4; m++){
            int row = tm*128 + wm + m*16 + g*4;
            int bb = row >> 8, nr = row & 255;
            unsigned short* ud = u16 + ((size_t)(bb*32 + hh)*256 + nr)*4 + c;
#pragma unroll
            for (int q = 0; q < 4; q++)
              ud[q*4] = f2h(acc[m][n][q] + bv);
          }
        }
      }
    }
  }
}

// ---------------- attention: 32 rows x 64 j per block (K/u amortized 2x) ----------------
// grid 1024 = B x 8 icp(32 rows) x 4 jq(64 j). XCD swizzle: 4 b per XCD.
// block 256 thr = 4 waves: rg=w>>1 (2x16 rows), ch=w&1 (2x32 j). loop h=0..31.
// Per head: 2 bias gloads (8KB slot, swizzled) + 2 side gloads
// (K-quarter 3KB | Q 1.5KB | u16 0.5KB | zeros) + 1 fpart store -> vmcnt(1).
// dp / mask-neg in regs (drained+pinned). exp via v_exp_f32, log2e folded.
#define SCALE 0.20412414523193154f     // 24^-0.5
#define INVSCALE 4.898979485566356f    // sqrt(24)
#define SL2 0.2944888918959693f        // SCALE*log2(e)
#define ML2 -23.083120654223414f       // -16*log2(e)
#define NEGS (100000.0f*INVSCALE)
__global__ __launch_bounds__(256, 4) void attn_kernel(
    const unsigned short* __restrict__ qkvh,
    const float* __restrict__ bias,
    const unsigned short* __restrict__ u16,
    const float* __restrict__ mask,
    const float* __restrict__ dp,
    const unsigned short* __restrict__ zws,
    float* __restrict__ fpart)
{
  int gswz = blockIdx.x;
  int lin = (gswz & 7)*128 + (gswz >> 3);   // 1024 = 8*128
  int b = lin >> 5, icp = (lin >> 2) & 7, jq = lin & 3;
  int i0 = icp*32, j00 = jq*64;
  int t = threadIdx.x;
  int wave = t >> 6, lane = t & 63;
  int rg = wave >> 1, ch = wave & 1;
  int fr = lane & 15, g = lane >> 4;
  int rl = rg*16 + fr;                // local row 0..31
  int hi32 = lane & 32;

  __shared__ __align__(16) char smem[32768];
  // bias dbuf 2x8192 @0 ; side dbuf 2x8192 @16384
  // side slot: K 3072 | Q @3072 1536 | u16 @4608 512 | zeros @5120 256 | waste

  // bias staging swizzle: dest a = k*4096 + t*16 -> row=a>>8 (256B rows), pc=(a>>4)&15
  int bsrc[2];
#pragma unroll
  for (int k = 0; k < 2; k++){
    int a = k*4096 + t*16;
    int row = a >> 8;
    int pc = (a >> 4) & 15;
    int lc = pc ^ (row & 7);
    bsrc[k] = row*1024 + lc*16;       // global row stride 1KB (256 j x 4B)
  }
  const char* bb0 = (const char*)bias
      + ((size_t)(b*NH_)*65536 + (size_t)i0*256 + j00)*4;   // + h*262144

  // side staging: granule G = k*256 + t -> slot byte G*16
  // G<192: K quarter; <288: Q rows; <320: u16 quarter; >=320: zeros (zws)
  const char* qkvhB = (const char*)qkvh;
  const char* kbase0 = qkvhB + ((size_t)(1024 + b*32))*12288 + jq*3072;  // +h*12288
  const char* qbase0 = qkvhB + ((size_t)(b*32))*12288 + (size_t)i0*48;   // +h*12288
  const char* ubase0 = (const char*)u16 + ((size_t)(b*NH_))*2048 + jq*512; // +h*2048
  const char* sbase[2]; size_t sstep[2];
#pragma unroll
  for (int k = 0; k < 2; k++){
    int G = k*256 + t;
    if (G < 192){ sbase[k] = kbase0 + G*16;            sstep[k] = 12288; }
    else if (G < 288){ sbase[k] = qbase0 + (G-192)*16; sstep[k] = 12288; }
    else if (G < 320){ sbase[k] = ubase0 + (G-288)*16; sstep[k] = 2048; }
    else { sbase[k] = (const char*)zws + ((G & 15))*16; sstep[k] = 0; }
  }

  #define ISSUE(hh) do { \
    int _par = (hh) & 1; \
    const char* _bp = bb0 + (size_t)(hh)*262144; \
    gload16(_bp + bsrc[0], smem + _par*8192 + wave*1024); \
    gload16(_bp + bsrc[1], smem + _par*8192 + 4096 + wave*1024); \
    gload16(sbase[0] + (size_t)(hh)*sstep[0], smem + 16384 + _par*8192 + wave*1024); \
    gload16(sbase[1] + (size_t)(hh)*sstep[1], smem + 16384 + _par*8192 + 4096 + wave*1024); \
  } while(0)

  // neg (pre-scaled by INVSCALE) + dpre into registers; drain + pin BEFORE the loop
  float4 nvs[2]; float4 dpre[6];
  {
    const float* mb = mask + b*N_ + j00;
#pragma unroll
    for (int jt = 0; jt < 2; jt++){
      float4 m4 = *(const float4*)(mb + ch*32 + jt*16 + g*4);
      nvs[jt].x = fmaf(m4.x, NEGS, -NEGS);
      nvs[jt].y = fmaf(m4.y, NEGS, -NEGS);
      nvs[jt].z = fmaf(m4.z, NEGS, -NEGS);
      nvs[jt].w = fmaf(m4.w, NEGS, -NEGS);
    }
    const float* dpb = dp + (size_t)(b*N_ + i0 + rl)*768;
#pragma unroll
    for (int jt = 0; jt < 2; jt++){
      const float4* dq = (const float4*)(dpb + (size_t)(j00 + ch*32 + jt*16 + g*4)*3);
      dpre[jt*3+0] = dq[0]; dpre[jt*3+1] = dq[1]; dpre[jt*3+2] = dq[2];
    }
  }
  asm volatile("s_waitcnt vmcnt(0)" ::: "memory");
  pin4(nvs[0]); pin4(nvs[1]);
#pragma unroll
  for (int k = 0; k < 6; k++) pin4(dpre[k]);

  ISSUE(0);
  gload16(zws, smem + 16384 + 5376);   // dummy into slot0 waste (parity for h=0)

  int swz = (fr & 7) << 4;
  float4* fp4 = (float4*)fpart;
  size_t fbase = (size_t)lin*2048 + rl*2 + ch;   // + h*64

#pragma unroll 1
  for (int h = 0; h < 32; h++){
    asm volatile("s_waitcnt vmcnt(1)" ::: "memory");
    __builtin_amdgcn_s_barrier();          // buf[h&1] published; buf[(h+1)&1] reads done
    if (h < 31) ISSUE(h+1);

    const char* bslot = smem + (h & 1)*8192;
    const char* sslot = smem + 16384 + (h & 1)*8192;
    const char* zp = sslot + 5120;

    const char* qa = (g < 3) ? (sslot + 3072 + rl*48 + g*16) : (zp + fr*16);
    f16x8 qf = __builtin_bit_cast(f16x8, *(const us8*)qa);

    float S = 0.f, a0 = 0.f, a1 = 0.f, a2 = 0.f;
#pragma unroll
    for (int jt = 0; jt < 2; jt++){
      int j0l = ch*32 + jt*16 + g*4;     // 0..63
      float4 bv = *(const float4*)(bslot + rl*256 + ((j0l*4) ^ swz));
      f32x4 cin;
      cin[0] = fmaf(bv.x, INVSCALE, nvs[jt].x);
      cin[1] = fmaf(bv.y, INVSCALE, nvs[jt].y);
      cin[2] = fmaf(bv.z, INVSCALE, nvs[jt].z);
      cin[3] = fmaf(bv.w, INVSCALE, nvs[jt].w);
      int kj = ch*32 + jt*16 + fr;
      // 48B rows; g==3 reads adjacent garbage — zeroed product via qf=0 chunk
      const char* ka = sslot + kj*48 + g*16;
      f16x8 kf = __builtin_bit_cast(f16x8, *(const us8*)ka);
      f32x4 sv = __builtin_amdgcn_mfma_f32_16x16x32_f16(kf, qf, cin, 0, 0, 0);
      float p0 = fexp2(fmaf(sv[0], SL2, ML2));
      float p1 = fexp2(fmaf(sv[1], SL2, ML2));
      float p2 = fexp2(fmaf(sv[2], SL2, ML2));
      float p3 = fexp2(fmaf(sv[3], SL2, ML2));
      S += p0 + p1 + p2 + p3;
      us8 ua = *(const us8*)(sslot + 4608 + j0l*8);
      us8 ub = *(const us8*)(sslot + 4608 + j0l*8 + 16);
      float4 d0 = dpre[jt*3], d1 = dpre[jt*3+1], d2 = dpre[jt*3+2];
      a0 += p0*h2f(ua[0])*d0.x + p1*h2f(ua[4])*d0.w + p2*h2f(ub[0])*d1.z + p3*h2f(ub[4])*d2.y;
      a1 += p0*h2f(ua[1])*d0.y + p1*h2f(ua[5])*d1.x + p2*h2f(ub[1])*d1.w + p3*h2f(ub[5])*d2.z;
      a2 += p0*h2f(ua[2])*d0.z + p1*h2f(ua[6])*d1.y + p2*h2f(ub[2])*d2.x + p3*h2f(ub[6])*d2.w;
    }
    S  += __shfl_xor(S, 16);   S  = red32(S, hi32);
    a0 += __shfl_xor(a0, 16);  a0 = red32(a0, hi32);
    a1 += __shfl_xor(a1, 16);  a1 = red32(a1, hi32);
    a2 += __shfl_xor(a2, 16);  a2 = red32(a2, hi32);
    if (lane < 16)
      fp4[fbase + (size_t)h*64] = make_float4(S, a0, a1, a2);
  }
  asm volatile("s_waitcnt vmcnt(0)" ::: "memory");
  #undef ISSUE
}

// ---------------- final: combine quarters/waves, normalize, add bf ----------------
__global__ __launch_bounds__(256) void final_kernel(const float* __restrict__ fpart,
    const float* __restrict__ bf1, const float* __restrict__ bf2, const float* __restrict__ bf3,
    float* __restrict__ out)
{
  int idx = blockIdx.x*256 + threadIdx.x;   // b*256 + i, 8192 total
  int b = idx >> 8, i = idx & 255;
  int icp = i >> 5, ii = i & 31;
  const float4* fp4 = (const float4*)fpart;
  size_t base = ((size_t)(b*8 + icp)*4)*2048 + ii*2;  // jq stride 2048 quads, h stride 64
  float acc0 = 0.f, acc1 = 0.f, acc2 = 0.f;
#pragma unroll 4
  for (int h = 0; h < 32; h++){
    float S = 0.f, A0 = 0.f, A1 = 0.f, A2 = 0.f;
#pragma unroll
    for (int jq = 0; jq < 4; jq++){
#pragma unroll
      for (int ch = 0; ch < 2; ch++){
        float4 v = fp4[base + (size_t)jq*2048 + (size_t)h*64 + ch];
        S += v.x; A0 += v.y; A1 += v.z; A2 += v.w;
      }
    }
    float rs = 1.0f / S;
    acc0 += A0*rs; acc1 += A1*rs; acc2 += A2*rs;
  }
  float* op = out + (size_t)idx*3;
  op[0] = acc0 + bf1[0];
  op[1] = acc1 + bf2[0];
  op[2] = acc2 + bf3[0];
}

extern "C" void kernel_launch(void* const* d_in, const int* in_sizes, int n_in,
                              void* d_out, int out_size, void* d_ws, size_t ws_size,
                              hipStream_t stream)
{
  const float* X    = (const float*)d_in[0];
  const float* bias = (const float*)d_in[1];
  const float* dp   = (const float*)d_in[2];
  const float* mask = (const float*)d_in[3];
  const float* Wi   = (const float*)d_in[4];
  const float* bi   = (const float*)d_in[5];
  const float* Wq   = (const float*)d_in[6];
  const float* bq   = (const float*)d_in[7];
  const float* Wk   = (const float*)d_in[8];
  const float* bk   = (const float*)d_in[9];
  const float* Wv   = (const float*)d_in[10];
  const float* bv   = (const float*)d_in[11];
  const float* Wf1  = (const float*)d_in[12];
  const float* bf1  = (const float*)d_in[13];
  const float* Wf2  = (const float*)d_in[14];
  const float* bf2  = (const float*)d_in[15];
  const float* Wf3  = (const float*)d_in[16];
  const float* bf3  = (const float*)d_in[17];
  float* out = (float*)d_out;

  unsigned short* xb   = (unsigned short*)d_ws;
  unsigned short* wib  = xb   + (size_t)M_*HS_;
  unsigned short* wqk  = wib  + (size_t)HS_*HS_;           // [1664][768]
  unsigned short* hb   = wqk  + (size_t)NQKU*HS_;
  unsigned short* qkvh = hb   + (size_t)M_*HS_;            // [2][1024][6144]
  unsigned short* u16a = qkvh + (size_t)2*1024*6144;       // [1024][256][4]
  float* bu    = (float*)(u16a + (size_t)B_*NH_*N_*4);     // [128]
  unsigned short* zws = (unsigned short*)(bu + 128);       // 256B zeros
  float* fpart = (float*)(zws + 128);

  {
    int n4 = M_*HS_/4;
    cvt_kernel<<<n4/256, 256, 0, stream>>>(X, xb, n4);
    int w4 = HS_*HS_/4;
    cvt_kernel<<<w4/256, 256, 0, stream>>>(Wi, wib, w4);
    cvt_kernel<<<w4/256, 256, 0, stream>>>(Wq, wqk, w4);
    cvt_kernel<<<w4/256, 256, 0, stream>>>(Wk, wqk + (size_t)768*768, w4);
    wuprep_kernel<<<128, 256, 0, stream>>>(Wv, bv, Wf1, Wf2, Wf3,
                                           wqk + (size_t)1536*768, bu, zws);
  }

  // h = gelu(X Wi^T + bi):  grid 64*6 = 384 (%8==0), row-major out
  gemm128_kernel<<<(M_/128)*(HS_/128), 256, 0, stream>>>(
      xb, wib, bi, bi, bi, hb, hb, u16a, M_, HS_, HS_, 1, 0);
  // [q|k|u] = h [Wq;Wk;Wu]^T + [bq;bk;bu]: grid 64*13 = 832 (%8==0), head-major out
  gemm128_kernel<<<(M_/128)*(NQKU/128), 256, 0, stream>>>(
      hb, wqk, bq, bk, bu, hb, qkvh, u16a, M_, NQKU, HS_, 0, 1);

  attn_kernel<<<B_*8*4, 256, 0, stream>>>(qkvh, bias, u16a, mask, dp, zws, fpart);

  final_kernel<<<(B_*N_)/256, 256, 0, stream>>>(fpart, bf1, bf2, bf3, out);
}

// Round 19
// 173.340 us; speedup vs baseline: 1.0884x; 1.0884x over previous
//
#include <hip/hip_runtime.h>
#include <hip/hip_fp16.h>

#define B_  32
#define N_  256
#define HS_ 768
#define NH_ 32
#define D_  24
#define M_  (B_*N_)   // 8192
#define NQKU 1664     // q 768 | k 768 | u 96 | pad 32

typedef unsigned short us8 __attribute__((ext_vector_type(8)));
typedef unsigned short us4v __attribute__((ext_vector_type(4)));
typedef _Float16 f16x8 __attribute__((ext_vector_type(8)));
typedef float f32x4 __attribute__((ext_vector_type(4)));

__device__ __forceinline__ unsigned short f2h(float x){
  return __half_as_ushort(__float2half(x));
}
__device__ __forceinline__ float h2f(unsigned short u){
  return __half2float(__ushort_as_half(u));
}
__device__ __forceinline__ void gload16(const void* g, void* l){
  __builtin_amdgcn_global_load_lds(
      (const __attribute__((address_space(1))) void*)g,
      (__attribute__((address_space(3))) void*)l, 16, 0, 0);
}
__device__ __forceinline__ void pin4(float4 &v){
  asm volatile("" : "+v"(v.x), "+v"(v.y), "+v"(v.z), "+v"(v.w));
}
__device__ __forceinline__ float fexp2(float x){
  float r; asm("v_exp_f32 %0, %1" : "=v"(r) : "v"(x)); return r;
}

// ---------------- mega prep: all fp32->fp16 conversions + Wu/bu in ONE launch --------
// blocks [0,6144): X cvt          (1572864 float4)
// [6144,6720): Wi cvt             (147456 float4)
// [6720,7296): Wq cvt -> wqk
// [7296,7872): Wk cvt -> wqk+147456(x4)
// [7872,8000): wuprep row r = blk-7872
__global__ __launch_bounds__(256) void prep_all_kernel(
    const float* __restrict__ X, const float* __restrict__ Wi,
    const float* __restrict__ Wq, const float* __restrict__ Wk,
    const float* __restrict__ Wv, const float* __restrict__ bvv,
    const float* __restrict__ Wf1, const float* __restrict__ Wf2, const float* __restrict__ Wf3,
    unsigned short* __restrict__ xb, unsigned short* __restrict__ wib,
    unsigned short* __restrict__ wqk, float* __restrict__ bu)
{
  int blk = blockIdx.x;
  int tt = threadIdx.x;
  if (blk < 7872){
    const float* src; ushort4* dst; int i;
    if (blk < 6144){ src = X;  dst = (ushort4*)xb;  i = blk*256 + tt; }
    else if (blk < 6720){ src = Wi; dst = (ushort4*)wib; i = (blk-6144)*256 + tt; }
    else if (blk < 7296){ src = Wq; dst = (ushort4*)wqk; i = (blk-6720)*256 + tt; }
    else { src = Wk; dst = (ushort4*)wqk + 147456; i = (blk-7296)*256 + tt; }
    float4 v = ((const float4*)src)[i];
    ushort4 o;
    o.x = f2h(v.x); o.y = f2h(v.y); o.z = f2h(v.z); o.w = f2h(v.w);
    dst[i] = o;
  } else {
    int r = blk - 7872;           // 0..127
    unsigned short* dst = wqk + (size_t)(1536 + r)*768;
    if (r < 96){
      int c = r >> 5, h = r & 31;
      const float* wf = (c == 0 ? Wf1 : c == 1 ? Wf2 : Wf3) + h*D_;
      float wfl[24];
#pragma unroll
      for (int d = 0; d < 24; d++) wfl[d] = wf[d];
      for (int kk = tt; kk < 768; kk += 256){
        float s = 0.f;
#pragma unroll
        for (int d = 0; d < 24; d++) s += wfl[d]*Wv[(size_t)(h*24 + d)*768 + kk];
        dst[kk] = f2h(s);
      }
      if (tt == 0){
        float s = 0.f;
        for (int d = 0; d < 24; d++) s += bvv[h*24 + d]*wfl[d];
        bu[r] = s;
      }
    } else {
      for (int kk = tt; kk < 768; kk += 256) dst[kk] = 0;
      if (tt == 0) bu[r] = 0.f;
    }
  }
}

// ---------------- GEMM 128x128, BK=64, global_load_lds, XOR-swizzled LDS ----------------
// mode 0: C row-major (+gelu). mode 1 (N=1664): tiles 0-5 -> q head-major,
// 6-11 -> k head-major, 12 -> u16 [bh][n][4] fp16 (cols 1632+ dropped).
__global__ __launch_bounds__(256) void gemm128_kernel(
    const unsigned short* __restrict__ A, const unsigned short* __restrict__ W,
    const float* __restrict__ b0, const float* __restrict__ b1, const float* __restrict__ b2,
    unsigned short* __restrict__ C, unsigned short* __restrict__ qkvh,
    unsigned short* __restrict__ u16,
    int M, int N, int K, int dogelu, int mode)
{
  __shared__ unsigned short As[128*64];
  __shared__ unsigned short Bs[128*64];
  int gswz = blockIdx.x;
  int chunkg = gridDim.x >> 3;
  int bid = (gswz & 7)*chunkg + (gswz >> 3);
  int tid = threadIdx.x;
  int nT = N >> 7;
  int tm = bid / nT;
  int tn = bid - tm*nT;
  int wave = tid >> 6, lane = tid & 63;
  int wm = (wave >> 1) << 6;
  int wn = (wave & 1) << 6;
  int fr = lane & 15;
  int g  = lane >> 4;

  size_t aoff[4], woff[4];
  int ldsb[4];
#pragma unroll
  for (int s4 = 0; s4 < 4; s4++){
    int ob = s4*4096 + tid*16;
    int r  = ob >> 7;
    int p  = (ob >> 4) & 7;
    int l  = p ^ (r & 7);
    aoff[s4] = ((size_t)(tm*128 + r)*K)*2 + l*16;
    woff[s4] = ((size_t)(tn*128 + r)*K)*2 + l*16;
    ldsb[s4] = s4*4096 + wave*1024;
  }
  const char* Ab = (const char*)A;
  const char* Wb = (const char*)W;
  char* AsB = (char*)As;
  char* BsB = (char*)Bs;

  f32x4 acc[4][4];
#pragma unroll
  for (int m = 0; m < 4; m++)
#pragma unroll
    for (int n = 0; n < 4; n++) acc[m][n] = (f32x4){0.f,0.f,0.f,0.f};

  for (int k0 = 0; k0 < K; k0 += 64){
    size_t kb = (size_t)k0*2;
#pragma unroll
    for (int s4 = 0; s4 < 4; s4++) gload16(Ab + aoff[s4] + kb, AsB + ldsb[s4]);
#pragma unroll
    for (int s4 = 0; s4 < 4; s4++) gload16(Wb + woff[s4] + kb, BsB + ldsb[s4]);
    __syncthreads();

    f16x8 af[4], bf[4];
#pragma unroll
    for (int m = 0; m < 4; m++){
      int row = wm + m*16 + fr;
      af[m] = __builtin_bit_cast(f16x8, *(const us8*)(AsB + row*128 + ((g ^ (row & 7))*16)));
    }
#pragma unroll
    for (int n = 0; n < 4; n++){
      int row = wn + n*16 + fr;
      bf[n] = __builtin_bit_cast(f16x8, *(const us8*)(BsB + row*128 + ((g ^ (row & 7))*16)));
    }
#pragma unroll
    for (int m = 0; m < 4; m++)
#pragma unroll
      for (int n = 0; n < 4; n++)
        acc[m][n] = __builtin_amdgcn_mfma_f32_16x16x32_f16(af[m], bf[n], acc[m][n], 0, 0, 0);

#pragma unroll
    for (int m = 0; m < 4; m++){
      int row = wm + m*16 + fr;
      af[m] = __builtin_bit_cast(f16x8, *(const us8*)(AsB + row*128 + (((g+4) ^ (row & 7))*16)));
    }
#pragma unroll
    for (int n = 0; n < 4; n++){
      int row = wn + n*16 + fr;
      bf[n] = __builtin_bit_cast(f16x8, *(const us8*)(BsB + row*128 + (((g+4) ^ (row & 7))*16)));
    }
#pragma unroll
    for (int m = 0; m < 4; m++)
#pragma unroll
      for (int n = 0; n < 4; n++)
        acc[m][n] = __builtin_amdgcn_mfma_f32_16x16x32_f16(af[m], bf[n], acc[m][n], 0, 0, 0);
    __syncthreads();
  }

  if (mode == 0){
    const float* bp = b0;
#pragma unroll
    for (int n = 0; n < 4; n++){
      int col = tn*128 + wn + n*16 + fr;
      float bv = bp[col];
#pragma unroll
      for (int m = 0; m < 4; m++){
        int row = tm*128 + wm + m*16 + g*4;
#pragma unroll
        for (int q = 0; q < 4; q++){
          float v = acc[m][n][q] + bv;
          if (dogelu) v = 0.5f*v*(1.0f + erff(v*0.70710678118654752f));
          C[(size_t)(row + q)*N + col] = f2h(v);
        }
      }
    }
  } else {
    int which = (tn < 6) ? 0 : (tn < 12) ? 1 : 2;
    if (which < 2){
      const float* bp = which ? (b1 - 768) : b0;
#pragma unroll
      for (int n = 0; n < 4; n++){
        int col = tn*128 + wn + n*16 + fr;
        float bv = bp[col];
        int hd = col - which*768;
        int hh = hd / 24;
        int dd = hd - hh*24;
#pragma unroll
        for (int m = 0; m < 4; m++){
          int row = tm*128 + wm + m*16 + g*4;
          size_t hmbase = ((size_t)(which*1024 + (row >> 8)*32 + hh))*6144 + (row & 255)*24 + dd;
#pragma unroll
          for (int q = 0; q < 4; q++)
            qkvh[hmbase + q*24] = f2h(acc[m][n][q] + bv);
        }
      }
    } else {
#pragma unroll
      for (int n = 0; n < 4; n++){
        int col = tn*128 + wn + n*16 + fr;
        int cu = col - 1536;
        if (cu < 96){
          int c = cu >> 5, hh = cu & 31;
          float bv = b2[cu];
#pragma unroll
          for (int m = 0; m < 4; m++){
            int row = tm*128 + wm + m*16 + g*4;
            int bb = row >> 8, nr = row & 255;
            unsigned short* ud = u16 + ((size_t)(bb*32 + hh)*256 + nr)*4 + c;
#pragma unroll
            for (int q = 0; q < 4; q++)
              ud[q*4] = f2h(acc[m][n][q] + bv);
          }
        }
      }
    }
  }
}

// ---------------- attention, j-split, depth-1 pipeline (round-14 structure) ----------------
// grid 1024 = B x 16 ichunks x 2 jhalves (XCD swizzle: 4 b per XCD).
// block 256 thr = 4 waves; 16 q-rows, 128 j's, loop h=0..31.
// Per head: 2 bias gloads (swizzled) + 2 side gloads (K 6KB | Q 768B | u16 1KB,
// all contiguous head-major). One barrier/head; counted vmcnt(1).
// dp / mask-neg in regs (drained+pinned). exp via v_exp_f32 with log2e folded.
#define SCALE 0.20412414523193154f     // 24^-0.5
#define INVSCALE 4.898979485566356f    // sqrt(24)
#define SL2 0.2944888918959693f        // SCALE*log2(e)
#define ML2 -23.083120654223414f       // -16*log2(e)
#define NEGS (100000.0f*INVSCALE)
__global__ __launch_bounds__(256, 4) void attn_kernel(
    const unsigned short* __restrict__ qkvh,
    const float* __restrict__ bias,
    const unsigned short* __restrict__ u16,
    const float* __restrict__ mask,
    const float* __restrict__ dp,
    float* __restrict__ fpart)
{
  int gswz = blockIdx.x;
  int lin = (gswz & 7)*128 + (gswz >> 3);   // 1024 = 8*128
  int b = lin >> 5, ic = (lin >> 1) & 15, jh = lin & 1;
  int i0 = ic*16, j00 = jh*128;
  int t = threadIdx.x;
  int wave = t >> 6, lane = t & 63;
  int ch = wave, fr = lane & 15, g = lane >> 4;

  __shared__ __align__(16) char smem[35840];
  // bias dbuf 2x8192 @0 ; side dbuf 2x8192 @16384 ; zp 2048 @32768 ; scratch @33792
  char* zp = smem + 32768;
  char* scratch = smem + 33792;

  // bias staging swizzle (both-sides): dest a=k*4096+t*16 -> row=a>>9, pc=(a>>4)&31
  int bsrc[2];
#pragma unroll
  for (int k = 0; k < 2; k++){
    int a = k*4096 + t*16;
    int row = a >> 9;
    int pc = (a >> 4) & 31;
    int lc = pc ^ (row & 7);
    bsrc[k] = row*1024 + lc*16;
  }
  const char* bb0 = (const char*)bias
      + ((size_t)(b*NH_)*65536 + (size_t)i0*256 + j00)*4;   // + h*262144

  // side staging (head-major, contiguous): granule G = k*256 + t -> slot byte G*16
  const char* qkvhB = (const char*)qkvh;
  const char* kbase0 = qkvhB + ((size_t)(1024 + b*32))*12288 + jh*6144;  // +h*12288
  const char* qbase0 = qkvhB + ((size_t)(b*32))*12288 + (size_t)i0*48;   // +h*12288
  const char* ubase0 = (const char*)u16 + ((size_t)(b*NH_))*2048 + jh*1024; // +h*2048
  const char* sbase[2]; size_t sstep[2];
#pragma unroll
  for (int k = 0; k < 2; k++){
    int G = k*256 + t;
    if (G < 384){ sbase[k] = kbase0 + G*16;            sstep[k] = 12288; }
    else if (G < 432){ sbase[k] = qbase0 + (G-384)*16; sstep[k] = 12288; }
    else if (G < 496){ sbase[k] = ubase0 + (G-432)*16; sstep[k] = 2048; }
    else { sbase[k] = ubase0; sstep[k] = 2048; }
  }

  #define ISSUE(hh) do { \
    int _par = (hh) & 1; \
    const char* _bp = bb0 + (size_t)(hh)*262144; \
    gload16(_bp + bsrc[0], smem + _par*8192 + wave*1024); \
    gload16(_bp + bsrc[1], smem + _par*8192 + 4096 + wave*1024); \
    gload16(sbase[0] + (size_t)(hh)*sstep[0], smem + 16384 + _par*8192 + wave*1024); \
    gload16(sbase[1] + (size_t)(hh)*sstep[1], smem + 16384 + _par*8192 + 4096 + wave*1024); \
  } while(0)

  // neg (pre-scaled by INVSCALE) + dpre into registers; drain + pin BEFORE the loop
  float4 nvs[2]; float4 dpre[6];
  {
    const float* mb = mask + b*N_ + j00;
#pragma unroll
    for (int jt = 0; jt < 2; jt++){
      float4 m4 = *(const float4*)(mb + ch*32 + jt*16 + g*4);
      nvs[jt].x = fmaf(m4.x, NEGS, -NEGS);
      nvs[jt].y = fmaf(m4.y, NEGS, -NEGS);
      nvs[jt].z = fmaf(m4.z, NEGS, -NEGS);
      nvs[jt].w = fmaf(m4.w, NEGS, -NEGS);
    }
    const float* dpb = dp + (size_t)(b*N_ + i0 + fr)*768;
#pragma unroll
    for (int jt = 0; jt < 2; jt++){
      const float4* dq = (const float4*)(dpb + (size_t)(j00 + ch*32 + jt*16 + g*4)*3);
      dpre[jt*3+0] = dq[0]; dpre[jt*3+1] = dq[1]; dpre[jt*3+2] = dq[2];
    }
  }
  asm volatile("s_waitcnt vmcnt(0)" ::: "memory");
  pin4(nvs[0]); pin4(nvs[1]);
#pragma unroll
  for (int k = 0; k < 6; k++) pin4(dpre[k]);

  ISSUE(0);
  gload16(mask + b*N_, scratch);   // dummy: keeps vmcnt parity for h=0
  if (t < 128) *(us8*)(zp + t*16) = (us8){0,0,0,0,0,0,0,0};
  asm volatile("s_waitcnt lgkmcnt(0)" ::: "memory");

  int swz = (fr & 7) << 4;
  float4* fp4 = (float4*)fpart;
  size_t fbase = (((size_t)(b*16 + ic)*2 + jh)*32)*64 + ch*16 + fr;  // + h*64

#pragma unroll 1
  for (int h = 0; h < 32; h++){
    asm volatile("s_waitcnt vmcnt(1)" ::: "memory");
    __builtin_amdgcn_s_barrier();          // buf[h&1] published; buf[(h+1)&1] reads done
    if (h < 31) ISSUE(h+1);

    const char* bslot = smem + (h & 1)*8192;
    const char* sslot = smem + 16384 + (h & 1)*8192;

    const char* qa = (g < 3) ? (sslot + 6144 + fr*48 + g*16) : (zp + fr*16);
    f16x8 qf = __builtin_bit_cast(f16x8, *(const us8*)qa);

    float S = 0.f, a0 = 0.f, a1 = 0.f, a2 = 0.f;
#pragma unroll
    for (int jt = 0; jt < 2; jt++){
      int j0l = ch*32 + jt*16 + g*4;
      float4 bv = *(const float4*)(bslot + fr*512 + ((j0l*4) ^ swz));
      f32x4 cin;
      cin[0] = fmaf(bv.x, INVSCALE, nvs[jt].x);
      cin[1] = fmaf(bv.y, INVSCALE, nvs[jt].y);
      cin[2] = fmaf(bv.z, INVSCALE, nvs[jt].z);
      cin[3] = fmaf(bv.w, INVSCALE, nvs[jt].w);
      int krow = ch*32 + jt*16 + fr;
      // 48B rows; g==3 reads adjacent garbage — zeroed product via qf=0 chunk
      const char* ka = sslot + krow*48 + g*16;
      f16x8 kf = __builtin_bit_cast(f16x8, *(const us8*)ka);
      f32x4 sv = __builtin_amdgcn_mfma_f32_16x16x32_f16(kf, qf, cin, 0, 0, 0);
      float p0 = fexp2(fmaf(sv[0], SL2, ML2));
      float p1 = fexp2(fmaf(sv[1], SL2, ML2));
      float p2 = fexp2(fmaf(sv[2], SL2, ML2));
      float p3 = fexp2(fmaf(sv[3], SL2, ML2));
      S += p0 + p1 + p2 + p3;
      us8 ua = *(const us8*)(sslot + 6912 + j0l*8);
      us8 ub = *(const us8*)(sslot + 6912 + j0l*8 + 16);
      float4 d0 = dpre[jt*3], d1 = dpre[jt*3+1], d2 = dpre[jt*3+2];
      a0 += p0*h2f(ua[0])*d0.x + p1*h2f(ua[4])*d0.w + p2*h2f(ub[0])*d1.z + p3*h2f(ub[4])*d2.y;
      a1 += p0*h2f(ua[1])*d0.y + p1*h2f(ua[5])*d1.x + p2*h2f(ub[1])*d1.w + p3*h2f(ub[5])*d2.z;
      a2 += p0*h2f(ua[2])*d0.z + p1*h2f(ua[6])*d1.y + p2*h2f(ub[2])*d2.x + p3*h2f(ub[6])*d2.w;
    }
    S  += __shfl_xor(S, 16);  S  += __shfl_xor(S, 32);
    a0 += __shfl_xor(a0, 16); a0 += __shfl_xor(a0, 32);
    a1 += __shfl_xor(a1, 16); a1 += __shfl_xor(a1, 32);
    a2 += __shfl_xor(a2, 16); a2 += __shfl_xor(a2, 32);
    if (lane < 16)
      fp4[fbase + (size_t)h*64] = make_float4(S, a0, a1, a2);
  }
  asm volatile("s_waitcnt vmcnt(0)" ::: "memory");
  #undef ISSUE
}

// ---------------- final: combine halves/waves, normalize, add bf ----------------
__global__ __launch_bounds__(256) void final_kernel(const float* __restrict__ fpart,
    const float* __restrict__ bf1, const float* __restrict__ bf2, const float* __restrict__ bf3,
    float* __restrict__ out)
{
  int idx = blockIdx.x*256 + threadIdx.x;   // b*256 + i, 8192 total
  int b = idx >> 8, i = idx & 255;
  int ic = i >> 4, ii = i & 15;
  const float4* fp4 = (const float4*)fpart;
  size_t base = ((size_t)(b*16 + ic)*2)*2048 + ii;  // jh stride 2048 quads, h stride 64
  float acc0 = 0.f, acc1 = 0.f, acc2 = 0.f;
#pragma unroll 4
  for (int h = 0; h < 32; h++){
    float S = 0.f, A0 = 0.f, A1 = 0.f, A2 = 0.f;
#pragma unroll
    for (int jh = 0; jh < 2; jh++){
#pragma unroll
      for (int ch = 0; ch < 4; ch++){
        float4 v = fp4[base + (size_t)jh*2048 + (size_t)h*64 + ch*16];
        S += v.x; A0 += v.y; A1 += v.z; A2 += v.w;
      }
    }
    float rs = 1.0f / S;
    acc0 += A0*rs; acc1 += A1*rs; acc2 += A2*rs;
  }
  float* op = out + (size_t)idx*3;
  op[0] = acc0 + bf1[0];
  op[1] = acc1 + bf2[0];
  op[2] = acc2 + bf3[0];
}

extern "C" void kernel_launch(void* const* d_in, const int* in_sizes, int n_in,
                              void* d_out, int out_size, void* d_ws, size_t ws_size,
                              hipStream_t stream)
{
  const float* X    = (const float*)d_in[0];
  const float* bias = (const float*)d_in[1];
  const float* dp   = (const float*)d_in[2];
  const float* mask = (const float*)d_in[3];
  const float* Wi   = (const float*)d_in[4];
  const float* bi   = (const float*)d_in[5];
  const float* Wq   = (const float*)d_in[6];
  const float* bq   = (const float*)d_in[7];
  const float* Wk   = (const float*)d_in[8];
  const float* bk   = (const float*)d_in[9];
  const float* Wv   = (const float*)d_in[10];
  const float* bv   = (const float*)d_in[11];
  const float* Wf1  = (const float*)d_in[12];
  const float* bf1  = (const float*)d_in[13];
  const float* Wf2  = (const float*)d_in[14];
  const float* bf2  = (const float*)d_in[15];
  const float* Wf3  = (const float*)d_in[16];
  const float* bf3  = (const float*)d_in[17];
  float* out = (float*)d_out;

  unsigned short* xb   = (unsigned short*)d_ws;
  unsigned short* wib  = xb   + (size_t)M_*HS_;
  unsigned short* wqk  = wib  + (size_t)HS_*HS_;           // [1664][768]
  unsigned short* hb   = wqk  + (size_t)NQKU*HS_;
  unsigned short* qkvh = hb   + (size_t)M_*HS_;            // [2][1024][6144]
  unsigned short* u16a = qkvh + (size_t)2*1024*6144;       // [1024][256][4]
  float* bu    = (float*)(u16a + (size_t)B_*NH_*N_*4);     // [128]
  float* fpart = bu + 128;

  // ALL conversions + Wu/bu in one launch (was 5 separate dispatches)
  prep_all_kernel<<<8000, 256, 0, stream>>>(X, Wi, Wq, Wk, Wv, bv,
                                            Wf1, Wf2, Wf3, xb, wib, wqk, bu);

  // h = gelu(X Wi^T + bi):  grid 64*6 = 384 (%8==0), row-major out
  gemm128_kernel<<<(M_/128)*(HS_/128), 256, 0, stream>>>(
      xb, wib, bi, bi, bi, hb, hb, u16a, M_, HS_, HS_, 1, 0);
  // [q|k|u] = h [Wq;Wk;Wu]^T + [bq;bk;bu]: grid 64*13 = 832 (%8==0), head-major out
  gemm128_kernel<<<(M_/128)*(NQKU/128), 256, 0, stream>>>(
      hb, wqk, bq, bk, bu, hb, qkvh, u16a, M_, NQKU, HS_, 0, 1);

  attn_kernel<<<B_*16*2, 256, 0, stream>>>(qkvh, bias, u16a, mask, dp, fpart);

  final_kernel<<<(B_*N_)/256, 256, 0, stream>>>(fpart, bf1, bf2, bf3, out);
}